// Round 1
// baseline (457.864 us; speedup 1.0000x reference)
//
#include <hip/hip_runtime.h>
#include <stdint.h>

#define EPSQ 1e-8f

typedef __attribute__((ext_vector_type(4))) int i32x4;

// ---- monotone float<->uint encoding so atomicMax(unsigned) orders floats ----
__device__ __forceinline__ unsigned enc_f(float f) {
    unsigned u = __float_as_uint(f);
    return (u & 0x80000000u) ? ~u : (u | 0x80000000u);
}
__device__ __forceinline__ float dec_f(unsigned u) {
    return (u & 0x80000000u) ? __uint_as_float(u & 0x7fffffffu)
                             : __uint_as_float(~u);
}

__device__ __forceinline__ float wave_max_f(float v) {
    #pragma unroll
    for (int off = 32; off; off >>= 1) v = fmaxf(v, __shfl_xor(v, off));
    return v;
}
__device__ __forceinline__ int wave_sum_i(int v) {
    #pragma unroll
    for (int off = 32; off; off >>= 1) v += __shfl_xor(v, off);
    return v;
}

// ---------------- global max(x) ----------------
__global__ __launch_bounds__(256) void k_max(const float4* __restrict__ in,
                                             long n4, unsigned* __restrict__ slot) {
    long i = (long)blockIdx.x * 256 + threadIdx.x;
    float m = -3.4e38f;
    for (; i < n4; i += (long)gridDim.x * 256) {
        float4 v = in[i];
        m = fmaxf(fmaxf(m, fmaxf(v.x, v.y)), fmaxf(v.z, v.w));
    }
    m = wave_max_f(m);
    if ((threadIdx.x & 63) == 0) atomicMax(slot, enc_f(m));
}

// ---------------- per-row weight quant: s_w, int8 q, row sum ----------------
__global__ __launch_bounds__(256) void k_quant_w(const float* __restrict__ w,
                                                 signed char* __restrict__ q,
                                                 float* __restrict__ s_out,
                                                 int* __restrict__ rs_out, int L) {
    int row = blockIdx.x;
    const float4* wr = (const float4*)(w + (long)row * L);
    int n4 = L >> 2;
    float m = 0.0f;
    for (int i = threadIdx.x; i < n4; i += 256) {
        float4 v = wr[i];
        m = fmaxf(m, fmaxf(fmaxf(fabsf(v.x), fabsf(v.y)),
                           fmaxf(fabsf(v.z), fabsf(v.w))));
    }
    __shared__ float sm[4];
    __shared__ int   si[4];
    m = wave_max_f(m);
    int wid = threadIdx.x >> 6;
    if ((threadIdx.x & 63) == 0) sm[wid] = m;
    __syncthreads();
    m = fmaxf(fmaxf(sm[0], sm[1]), fmaxf(sm[2], sm[3]));
    float s = fmaxf(m, EPSQ) / 127.0f;   // exact same fp32 ops as reference

    char4* qr = (char4*)(q + (long)row * L);
    int isum = 0;
    for (int i = threadIdx.x; i < n4; i += 256) {
        float4 v = wr[i];
        int a = min(max((int)rintf(v.x / s), -128), 127);
        int b = min(max((int)rintf(v.y / s), -128), 127);
        int c = min(max((int)rintf(v.z / s), -128), 127);
        int d = min(max((int)rintf(v.w / s), -128), 127);
        isum += a + b + c + d;
        char4 cc; cc.x = (char)a; cc.y = (char)b; cc.z = (char)c; cc.w = (char)d;
        qr[i] = cc;
    }
    isum = wave_sum_i(isum);
    if ((threadIdx.x & 63) == 0) si[wid] = isum;
    __syncthreads();
    if (threadIdx.x == 0) {
        s_out[row]  = s;
        rs_out[row] = si[0] + si[1] + si[2] + si[3];
    }
}

// ---------------- activation quant x -> int8 (offset -128) ----------------
__global__ __launch_bounds__(256) void k_quant_act(const float4* __restrict__ in,
                                                   char4* __restrict__ out, long n4,
                                                   const unsigned* __restrict__ slot) {
    float s = fmaxf(dec_f(*slot), EPSQ) / 255.0f;
    long i = (long)blockIdx.x * 256 + threadIdx.x;
    for (; i < n4; i += (long)gridDim.x * 256) {
        float4 v = in[i];
        int a = min(max((int)rintf(v.x / s), 0), 255) - 128;
        int b = min(max((int)rintf(v.y / s), 0), 255) - 128;
        int c = min(max((int)rintf(v.z / s), 0), 255) - 128;
        int d = min(max((int)rintf(v.w / s), 0), 255) - 128;
        char4 cc; cc.x = (char)a; cc.y = (char)b; cc.z = (char)c; cc.w = (char)d;
        out[i] = cc;
    }
}

// ---------------- async global -> LDS, 16B per lane ----------------
__device__ __forceinline__ void gl_lds16(const signed char* g, signed char* l) {
    __builtin_amdgcn_global_load_lds(
        (const __attribute__((address_space(1))) unsigned int*)g,
        (__attribute__((address_space(3))) unsigned int*)l, 16, 0, 0);
}

// ---------------- i8 GEMM: C[m,n] = dot(A[m,:], B[n,:]) + epilogue ----------
// MODE 0: out = s*(acc+corr+bint) -> fp32 store (GEMM2)
// MODE 1: relu -> global max only (GEMM1 pass 1)
// MODE 2: relu -> uint8 quant (offset -128) -> int8 store (GEMM1 pass 2)
template<int MODE>
__global__ __launch_bounds__(256) void k_gemm_i8(
    const signed char* __restrict__ A,   // [M][K]
    const signed char* __restrict__ B,   // [N][K]
    const float* __restrict__ s_w,       // [N]
    const int* __restrict__ rowsum,      // [N] sum of int8 weights per row
    const float* __restrict__ bias,      // [N]
    const unsigned* __restrict__ act_slot,  // encoded max of input activation
    float* __restrict__ Cf,              // MODE 0
    signed char* __restrict__ Cq,        // MODE 2
    unsigned* __restrict__ omax_slot,    // MODE 1: target; MODE 2: source
    int M, int N, int K) {
    __shared__ __align__(16) signed char Als[128 * 64];
    __shared__ __align__(16) signed char Bls[128 * 64];

    const int t  = threadIdx.x;
    const int m0 = blockIdx.y * 128;
    const int n0 = blockIdx.x * 128;

    // staging: thread t loads 16B chunks; LDS dest = linear*16 (wave-uniform
    // base + lane*16). XOR-swizzle applied on the SOURCE k-group so fragment
    // ds_read_b128 is 2-way-bank-aliased (free) instead of grouped.
    const int r0  = t >> 2, g0 = t & 3;
    const int r1  = r0 + 64;
    const int sw0 = (r0 ^ (r0 >> 2)) & 3;
    const int sw1 = (r1 ^ (r1 >> 2)) & 3;
    const signed char* a_src0 = A + (long)(m0 + r0) * K + ((g0 ^ sw0) << 4);
    const signed char* a_src1 = A + (long)(m0 + r1) * K + ((g0 ^ sw1) << 4);
    const signed char* b_src0 = B + (long)(n0 + r0) * K + ((g0 ^ sw0) << 4);
    const signed char* b_src1 = B + (long)(n0 + r1) * K + ((g0 ^ sw1) << 4);
    signed char* a_dst0 = Als + t * 16;
    signed char* a_dst1 = Als + (t + 256) * 16;
    signed char* b_dst0 = Bls + t * 16;
    signed char* b_dst1 = Bls + (t + 256) * 16;

    const int lane = t & 63;
    const int wid  = t >> 6;
    const int wrow = (wid >> 1) * 64;
    const int wcol = (wid & 1) * 64;
    const int q    = lane >> 4;       // k-quad for A/B frags; row-quad for C/D
    const int mr   = lane & 15;       // row within 16 for A/B; col for C/D
    const int sfr  = (mr ^ (mr >> 2)) & 3;
    const int fcol = ((q ^ sfr) << 4);  // physical 16B col group in LDS row

    i32x4 acc[4][4];
    #pragma unroll
    for (int i = 0; i < 4; i++)
        #pragma unroll
        for (int j = 0; j < 4; j++) acc[i][j] = (i32x4){0, 0, 0, 0};

    int a_off[4], b_off[4];
    #pragma unroll
    for (int i = 0; i < 4; i++) a_off[i] = (wrow + i * 16 + mr) * 64 + fcol;
    #pragma unroll
    for (int j = 0; j < 4; j++) b_off[j] = (wcol + j * 16 + mr) * 64 + fcol;

    for (int k0 = 0; k0 < K; k0 += 64) {
        __syncthreads();                 // LDS free from previous iter's reads
        gl_lds16(a_src0 + k0, a_dst0);
        gl_lds16(a_src1 + k0, a_dst1);
        gl_lds16(b_src0 + k0, b_dst0);
        gl_lds16(b_src1 + k0, b_dst1);
        __syncthreads();                 // compiler drains vmcnt before barrier

        i32x4 af[4], bf[4];
        #pragma unroll
        for (int i = 0; i < 4; i++) af[i] = *(const i32x4*)(Als + a_off[i]);
        #pragma unroll
        for (int j = 0; j < 4; j++) bf[j] = *(const i32x4*)(Bls + b_off[j]);
        #pragma unroll
        for (int i = 0; i < 4; i++)
            #pragma unroll
            for (int j = 0; j < 4; j++)
                acc[i][j] = __builtin_amdgcn_mfma_i32_16x16x64_i8(
                    af[i], bf[j], acc[i][j], 0, 0, 0);
    }

    // ---- epilogue ----
    const float s_act = fmaxf(dec_f(*act_slot), EPSQ) / 255.0f;
    float s_oq = 1.0f;
    if (MODE == 2) s_oq = fmaxf(dec_f(*omax_slot), EPSQ) / 255.0f;
    float lmax = 0.0f;

    #pragma unroll
    for (int j = 0; j < 4; j++) {
        int gn = n0 + wcol + j * 16 + mr;       // C/D col = lane&15
        float sw   = s_w[gn];
        float ssc  = s_act * sw;
        float bint = rintf(bias[gn] / ssc);     // quantized-bias integer
        int   icor = 128 * rowsum[gn];          // uint8 zero-point correction
        #pragma unroll
        for (int i = 0; i < 4; i++) {
            #pragma unroll
            for (int r = 0; r < 4; r++) {
                int gm = m0 + wrow + i * 16 + q * 4 + r;  // C/D row
                float h = ssc * ((float)(acc[i][j][r] + icor) + bint);
                if (MODE >= 1) h = fmaxf(h, 0.0f);
                if (MODE == 0) Cf[(long)gm * N + gn] = h;
                if (MODE == 1) lmax = fmaxf(lmax, h);
                if (MODE == 2) {
                    int qv = min(max((int)rintf(h / s_oq), 0), 255) - 128;
                    Cq[(long)gm * N + gn] = (signed char)qv;
                }
            }
        }
    }
    if (MODE == 1) {
        lmax = wave_max_f(lmax);
        if (lane == 0) atomicMax(omax_slot, enc_f(lmax));
    }
}

extern "C" void kernel_launch(void* const* d_in, const int* in_sizes, int n_in,
                              void* d_out, int out_size, void* d_ws, size_t ws_size,
                              hipStream_t stream) {
    const float* x  = (const float*)d_in[0];  // [4,2048,1024]
    const float* w1 = (const float*)d_in[1];  // [4096,1024]
    const float* b1 = (const float*)d_in[2];  // [4096]
    const float* w2 = (const float*)d_in[3];  // [1024,4096]
    const float* b2 = (const float*)d_in[4];  // [1024]
    float* out = (float*)d_out;               // [4,2048,1024] fp32

    const int M = 8192, D = 1024, F = 4096;

    char* ws = (char*)d_ws;
    size_t off = 0;
    unsigned* slots = (unsigned*)ws;               off += 256;  // [0]=max x, [1]=max h
    signed char* xi  = (signed char*)(ws + off);   off += (size_t)M * D;  // 8 MB
    signed char* w1q = (signed char*)(ws + off);   off += (size_t)F * D;  // 4 MB
    signed char* w2q = (signed char*)(ws + off);   off += (size_t)D * F;  // 4 MB
    float* sw1 = (float*)(ws + off);               off += (size_t)F * 4;
    float* sw2 = (float*)(ws + off);               off += (size_t)D * 4;
    int* rs1   = (int*)(ws + off);                 off += (size_t)F * 4;
    int* rs2   = (int*)(ws + off);                 off += (size_t)D * 4;
    signed char* hq = (signed char*)(ws + off);    off += (size_t)M * F;  // 32 MB

    hipMemsetAsync(slots, 0, 8, stream);  // 0 == encoded -inf-ish

    k_max<<<dim3(2048), dim3(256), 0, stream>>>((const float4*)x,
                                                (long)M * D / 4, slots + 0);
    k_quant_w<<<dim3(F), dim3(256), 0, stream>>>(w1, w1q, sw1, rs1, D);
    k_quant_w<<<dim3(D), dim3(256), 0, stream>>>(w2, w2q, sw2, rs2, F);
    k_quant_act<<<dim3(2048), dim3(256), 0, stream>>>((const float4*)x, (char4*)xi,
                                                      (long)M * D / 4, slots + 0);
    // GEMM1 pass 1: max(relu(h)) only
    k_gemm_i8<1><<<dim3(F / 128, M / 128), dim3(256), 0, stream>>>(
        xi, w1q, sw1, rs1, b1, slots + 0, nullptr, nullptr, slots + 1, M, F, D);
    // GEMM1 pass 2: write quantized h (int8, offset -128)
    k_gemm_i8<2><<<dim3(F / 128, M / 128), dim3(256), 0, stream>>>(
        xi, w1q, sw1, rs1, b1, slots + 0, nullptr, hq, slots + 1, M, F, D);
    // GEMM2: fp32 output
    k_gemm_i8<0><<<dim3(D / 128, M / 128), dim3(256), 0, stream>>>(
        hq, w2q, sw2, rs2, b2, slots + 1, out, nullptr, nullptr, M, D, F);

    (void)in_sizes; (void)n_in; (void)out_size; (void)ws_size;
}

// Round 3
// 406.884 us; speedup vs baseline: 1.1253x; 1.1253x over previous
//
#include <hip/hip_runtime.h>
#include <stdint.h>

#define EPSQ 1e-8f

typedef __attribute__((ext_vector_type(4))) int i32x4;

// ---- monotone float<->uint encoding so atomicMax(unsigned) orders floats ----
__device__ __forceinline__ unsigned enc_f(float f) {
    unsigned u = __float_as_uint(f);
    return (u & 0x80000000u) ? ~u : (u | 0x80000000u);
}
__device__ __forceinline__ float dec_f(unsigned u) {
    return (u & 0x80000000u) ? __uint_as_float(u & 0x7fffffffu)
                             : __uint_as_float(~u);
}

__device__ __forceinline__ float wave_max_f(float v) {
    #pragma unroll
    for (int off = 32; off; off >>= 1) v = fmaxf(v, __shfl_xor(v, off));
    return v;
}
__device__ __forceinline__ int wave_sum_i(int v) {
    #pragma unroll
    for (int off = 32; off; off >>= 1) v += __shfl_xor(v, off);
    return v;
}

// ---------------- fused prep: global max(x) + per-row quant of w1, w2 -------
// blocks [0,2048): x-max grid-stride; [2048,6144): w1 rows; [6144,7168): w2 rows
__global__ __launch_bounds__(256) void k_prep(
    const float4* __restrict__ x, long n4x, unsigned* __restrict__ slot,
    const float* __restrict__ w1, signed char* __restrict__ w1q,
    float* __restrict__ sw1, int* __restrict__ rs1,
    const float* __restrict__ w2, signed char* __restrict__ w2q,
    float* __restrict__ sw2, int* __restrict__ rs2) {
    int b = blockIdx.x;
    if (b < 2048) {
        long i = (long)b * 256 + threadIdx.x;
        float m = -3.4e38f;
        for (; i < n4x; i += 2048L * 256) {
            float4 v = x[i];
            m = fmaxf(fmaxf(m, fmaxf(v.x, v.y)), fmaxf(v.z, v.w));
        }
        m = wave_max_f(m);
        if ((threadIdx.x & 63) == 0) atomicMax(slot, enc_f(m));
        return;
    }
    const float* w; signed char* q; float* s_out; int* rs_out; int row, L;
    if (b < 2048 + 4096) { row = b - 2048; w = w1; q = w1q; s_out = sw1; rs_out = rs1; L = 1024; }
    else                 { row = b - 6144; w = w2; q = w2q; s_out = sw2; rs_out = rs2; L = 4096; }

    const float4* wr = (const float4*)(w + (long)row * L);
    int n4 = L >> 2;
    float m = 0.0f;
    for (int i = threadIdx.x; i < n4; i += 256) {
        float4 v = wr[i];
        m = fmaxf(m, fmaxf(fmaxf(fabsf(v.x), fabsf(v.y)),
                           fmaxf(fabsf(v.z), fabsf(v.w))));
    }
    __shared__ float sm[4];
    __shared__ int   si[4];
    m = wave_max_f(m);
    int wid = threadIdx.x >> 6;
    if ((threadIdx.x & 63) == 0) sm[wid] = m;
    __syncthreads();
    m = fmaxf(fmaxf(sm[0], sm[1]), fmaxf(sm[2], sm[3]));
    float s = fmaxf(m, EPSQ) / 127.0f;   // same fp32 ops as reference

    char4* qr = (char4*)(q + (long)row * L);
    int isum = 0;
    for (int i = threadIdx.x; i < n4; i += 256) {
        float4 v = wr[i];
        int a = min(max((int)rintf(v.x / s), -128), 127);
        int bb = min(max((int)rintf(v.y / s), -128), 127);
        int c = min(max((int)rintf(v.z / s), -128), 127);
        int d = min(max((int)rintf(v.w / s), -128), 127);
        isum += a + bb + c + d;
        char4 cc; cc.x = (char)a; cc.y = (char)bb; cc.z = (char)c; cc.w = (char)d;
        qr[i] = cc;
    }
    isum = wave_sum_i(isum);
    if ((threadIdx.x & 63) == 0) si[wid] = isum;
    __syncthreads();
    if (threadIdx.x == 0) {
        s_out[row]  = s;
        rs_out[row] = si[0] + si[1] + si[2] + si[3];
    }
}

// ---------------- activation quant x -> int8 (offset -128) ----------------
__global__ __launch_bounds__(256) void k_quant_act(const float4* __restrict__ in,
                                                   char4* __restrict__ out, long n4,
                                                   const unsigned* __restrict__ slot) {
    float s = fmaxf(dec_f(*slot), EPSQ) / 255.0f;
    long i = (long)blockIdx.x * 256 + threadIdx.x;
    for (; i < n4; i += (long)gridDim.x * 256) {
        float4 v = in[i];
        int a = min(max((int)rintf(v.x / s), 0), 255) - 128;
        int b = min(max((int)rintf(v.y / s), 0), 255) - 128;
        int c = min(max((int)rintf(v.z / s), 0), 255) - 128;
        int d = min(max((int)rintf(v.w / s), 0), 255) - 128;
        char4 cc; cc.x = (char)a; cc.y = (char)b; cc.z = (char)c; cc.w = (char)d;
        out[i] = cc;
    }
}

// ---------------- async global -> LDS, 16B per lane ----------------
__device__ __forceinline__ void gl_lds16(const signed char* g, signed char* l) {
    __builtin_amdgcn_global_load_lds(
        (const __attribute__((address_space(1))) unsigned int*)g,
        (__attribute__((address_space(3))) unsigned int*)l, 16, 0, 0);
}

// ---------------- i8 GEMM, BK=128, 2-barrier (m97-proven shape) -------------
// LDS panel-major layout per slab (128 rows x 128 k-bytes = 16KB):
//   panel p (16 rows) at p*2048; byte (g*256 + r*16 + b) = row p*16+r, k g*16+b.
// Wave w stages its own contiguous 4KB (panels 2w,2w+1) with 8 gl_lds16;
// fragment reads are wave-contiguous 1024B ds_read_b128 (conflict-free).
// MODE 0: fp32 store (GEMM2); MODE 1: relu->global max only; MODE 2: relu->u8 quant store.
template<int MODE>
__global__ __launch_bounds__(256, 3) void k_gemm_i8(
    const signed char* __restrict__ A,   // [M][K]
    const signed char* __restrict__ B,   // [N][K]
    const float* __restrict__ s_w,       // [N]
    const int* __restrict__ rowsum,      // [N]
    const float* __restrict__ bias,      // [N]
    const unsigned* __restrict__ act_slot,
    float* __restrict__ Cf,              // MODE 0
    signed char* __restrict__ Cq,        // MODE 2
    unsigned* __restrict__ omax_slot,    // MODE 1: target; MODE 2: source
    int M, int N, long K) {
    __shared__ __align__(16) signed char Als[16384];
    __shared__ __align__(16) signed char Bls[16384];
    __shared__ float red[4];

    const int t    = threadIdx.x;
    const int lane = t & 63;
    const int w    = t >> 6;
    const int m0   = blockIdx.y * 128;
    const int n0   = blockIdx.x * 128;
    const int mr   = lane & 15;   // row-in-panel / C-D col-in-16
    const int qq   = lane >> 4;   // k-group / C-D row-quad

    // staging: lane fetches row (m0 + w*32 + mr [+16]), k-bytes (qq*16 [+64])
    const signed char* a0 = A + (long)(m0 + w * 32 + mr) * K + qq * 16;
    const signed char* b0 = B + (long)(n0 + w * 32 + mr) * K + qq * 16;
    signed char* ad = Als + w * 4096 + lane * 16;
    signed char* bd = Bls + w * 4096 + lane * 16;

    const int wrow = (w >> 1) * 64;
    const int wcol = (w & 1) * 64;
    const int a_base = (w >> 1) * 8192 + lane * 16;
    const int b_base = (w & 1) * 8192 + lane * 16;

    i32x4 acc[4][4];
    #pragma unroll
    for (int i = 0; i < 4; i++)
        #pragma unroll
        for (int j = 0; j < 4; j++) acc[i][j] = (i32x4){0, 0, 0, 0};

    for (long k0 = 0; k0 < K; k0 += 128) {
        __syncthreads();                    // previous iter's reads done
        gl_lds16(a0 + k0,               ad);
        gl_lds16(a0 + k0 + 64,          ad + 1024);
        gl_lds16(a0 + k0 + 16 * K,      ad + 2048);
        gl_lds16(a0 + k0 + 16 * K + 64, ad + 3072);
        gl_lds16(b0 + k0,               bd);
        gl_lds16(b0 + k0 + 64,          bd + 1024);
        gl_lds16(b0 + k0 + 16 * K,      bd + 2048);
        gl_lds16(b0 + k0 + 16 * K + 64, bd + 3072);
        __syncthreads();                    // vmcnt(0) drain: staging visible

        #pragma unroll
        for (int kk = 0; kk < 2; kk++) {
            i32x4 af[4], bf[4];
            #pragma unroll
            for (int i = 0; i < 4; i++)
                af[i] = *(const i32x4*)(Als + a_base + i * 2048 + kk * 1024);
            #pragma unroll
            for (int j = 0; j < 4; j++)
                bf[j] = *(const i32x4*)(Bls + b_base + j * 2048 + kk * 1024);
            #pragma unroll
            for (int i = 0; i < 4; i++)
                #pragma unroll
                for (int j = 0; j < 4; j++)
                    acc[i][j] = __builtin_amdgcn_mfma_i32_16x16x64_i8(
                        af[i], bf[j], acc[i][j], 0, 0, 0);
        }
    }

    // ---- epilogue ----
    const float s_act = fmaxf(dec_f(*act_slot), EPSQ) / 255.0f;

    if (MODE == 1) {
        // max(relu(h)); h = ssc*(v+bint) monotone in integer v per column
        float lmax = 0.0f;
        #pragma unroll
        for (int j = 0; j < 4; j++) {
            int im = -2147483647 - 1;
            #pragma unroll
            for (int i = 0; i < 4; i++)
                #pragma unroll
                for (int r = 0; r < 4; r++) im = max(im, acc[i][j][r]);
            int gn = n0 + wcol + j * 16 + mr;
            float ssc  = s_act * s_w[gn];
            float bint = rintf(bias[gn] / ssc);
            float h = ssc * ((float)(im + 128 * rowsum[gn]) + bint);
            lmax = fmaxf(lmax, h);
        }
        lmax = fmaxf(lmax, 0.0f);
        lmax = wave_max_f(lmax);
        if (lane == 0) red[w] = lmax;
        __syncthreads();
        if (t == 0)
            atomicMax(omax_slot,
                      enc_f(fmaxf(fmaxf(red[0], red[1]), fmaxf(red[2], red[3]))));
        return;
    }

    float s_oq = 1.0f;
    if (MODE == 2) s_oq = fmaxf(dec_f(*omax_slot), EPSQ) / 255.0f;

    #pragma unroll
    for (int j = 0; j < 4; j++) {
        int gn = n0 + wcol + j * 16 + mr;       // C/D col = lane&15
        float ssc  = s_act * s_w[gn];
        float bint = rintf(bias[gn] / ssc);
        int   icor = 128 * rowsum[gn];          // uint8 zero-point correction
        float fq   = (MODE == 2) ? (ssc / s_oq) : 0.0f;
        #pragma unroll
        for (int i = 0; i < 4; i++) {
            #pragma unroll
            for (int r = 0; r < 4; r++) {
                int gm = m0 + wrow + i * 16 + qq * 4 + r;  // C/D row
                float v = (float)(acc[i][j][r] + icor) + bint;
                if (MODE == 0) {
                    Cf[(long)gm * N + gn] = ssc * v;
                } else {
                    int qv = min(max((int)rintf(fq * v), 0), 255) - 128;
                    Cq[(long)gm * N + gn] = (signed char)qv;
                }
            }
        }
    }
}

extern "C" void kernel_launch(void* const* d_in, const int* in_sizes, int n_in,
                              void* d_out, int out_size, void* d_ws, size_t ws_size,
                              hipStream_t stream) {
    const float* x  = (const float*)d_in[0];  // [4,2048,1024]
    const float* w1 = (const float*)d_in[1];  // [4096,1024]
    const float* b1 = (const float*)d_in[2];  // [4096]
    const float* w2 = (const float*)d_in[3];  // [1024,4096]
    const float* b2 = (const float*)d_in[4];  // [1024]
    float* out = (float*)d_out;               // [4,2048,1024] fp32

    const int M = 8192, D = 1024, F = 4096;

    char* ws = (char*)d_ws;
    size_t off = 0;
    unsigned* slots = (unsigned*)ws;               off += 256;  // [0]=max x, [1]=max h
    signed char* xi  = (signed char*)(ws + off);   off += (size_t)M * D;  // 8 MB
    signed char* w1q = (signed char*)(ws + off);   off += (size_t)F * D;  // 4 MB
    signed char* w2q = (signed char*)(ws + off);   off += (size_t)D * F;  // 4 MB
    float* sw1 = (float*)(ws + off);               off += (size_t)F * 4;
    float* sw2 = (float*)(ws + off);               off += (size_t)D * 4;
    int* rs1   = (int*)(ws + off);                 off += (size_t)F * 4;
    int* rs2   = (int*)(ws + off);                 off += (size_t)D * 4;
    signed char* hq = (signed char*)(ws + off);    off += (size_t)M * F;  // 32 MB

    hipMemsetAsync(slots, 0, 8, stream);  // 0 < any encoded real value

    k_prep<<<dim3(2048 + F + D), dim3(256), 0, stream>>>(
        (const float4*)x, (long)M * D / 4, slots + 0,
        w1, w1q, sw1, rs1, w2, w2q, sw2, rs2);
    k_quant_act<<<dim3(2048), dim3(256), 0, stream>>>((const float4*)x, (char4*)xi,
                                                      (long)M * D / 4, slots + 0);
    // GEMM1 pass 1: max(relu(h)) only
    k_gemm_i8<1><<<dim3(F / 128, M / 128), dim3(256), 0, stream>>>(
        xi, w1q, sw1, rs1, b1, slots + 0, nullptr, nullptr, slots + 1, M, F, (long)D);
    // GEMM1 pass 2: write quantized h (int8, offset -128)
    k_gemm_i8<2><<<dim3(F / 128, M / 128), dim3(256), 0, stream>>>(
        xi, w1q, sw1, rs1, b1, slots + 0, nullptr, hq, slots + 1, M, F, (long)D);
    // GEMM2: fp32 output
    k_gemm_i8<0><<<dim3(D / 128, M / 128), dim3(256), 0, stream>>>(
        hq, w2q, sw2, rs2, b2, slots + 1, out, nullptr, nullptr, M, D, (long)F);

    (void)in_sizes; (void)n_in; (void)out_size; (void)ws_size;
}

// Round 4
// 318.476 us; speedup vs baseline: 1.4377x; 1.2776x over previous
//
#include <hip/hip_runtime.h>
#include <stdint.h>

#define EPSQ 1e-8f

typedef __attribute__((ext_vector_type(4))) int i32x4;

// ---- monotone float<->uint encoding so atomicMax(unsigned) orders floats ----
__device__ __forceinline__ unsigned enc_f(float f) {
    unsigned u = __float_as_uint(f);
    return (u & 0x80000000u) ? ~u : (u | 0x80000000u);
}
__device__ __forceinline__ float dec_f(unsigned u) {
    return (u & 0x80000000u) ? __uint_as_float(u & 0x7fffffffu)
                             : __uint_as_float(~u);
}

__device__ __forceinline__ float wave_max_f(float v) {
    #pragma unroll
    for (int off = 32; off; off >>= 1) v = fmaxf(v, __shfl_xor(v, off));
    return v;
}
__device__ __forceinline__ int wave_sum_i(int v) {
    #pragma unroll
    for (int off = 32; off; off >>= 1) v += __shfl_xor(v, off);
    return v;
}

// ---------------- fused prep: x partial max + per-row quant of w1, w2 -------
// blocks [0,2048): x-max grid-stride -> partials[b] (NO atomics);
// [2048,6144): w1 rows; [6144,7168): w2 rows
__global__ __launch_bounds__(256) void k_prep(
    const float4* __restrict__ x, long n4x, float* __restrict__ partials,
    const float* __restrict__ w1, signed char* __restrict__ w1q,
    float* __restrict__ sw1, int* __restrict__ rs1,
    const float* __restrict__ w2, signed char* __restrict__ w2q,
    float* __restrict__ sw2, int* __restrict__ rs2) {
    __shared__ float sm[4];
    __shared__ int   si[4];
    int b = blockIdx.x;
    int wid = threadIdx.x >> 6;
    if (b < 2048) {
        long i = (long)b * 256 + threadIdx.x;
        float m = -3.4e38f;
        for (; i < n4x; i += 2048L * 256) {
            float4 v = x[i];
            m = fmaxf(fmaxf(m, fmaxf(v.x, v.y)), fmaxf(v.z, v.w));
        }
        m = wave_max_f(m);
        if ((threadIdx.x & 63) == 0) sm[wid] = m;
        __syncthreads();
        if (threadIdx.x == 0)
            partials[b] = fmaxf(fmaxf(sm[0], sm[1]), fmaxf(sm[2], sm[3]));
        return;
    }
    const float* w; signed char* q; float* s_out; int* rs_out; int row, L;
    if (b < 2048 + 4096) { row = b - 2048; w = w1; q = w1q; s_out = sw1; rs_out = rs1; L = 1024; }
    else                 { row = b - 6144; w = w2; q = w2q; s_out = sw2; rs_out = rs2; L = 4096; }

    const float4* wr = (const float4*)(w + (long)row * L);
    int n4 = L >> 2;
    float m = 0.0f;
    for (int i = threadIdx.x; i < n4; i += 256) {
        float4 v = wr[i];
        m = fmaxf(m, fmaxf(fmaxf(fabsf(v.x), fabsf(v.y)),
                           fmaxf(fabsf(v.z), fabsf(v.w))));
    }
    m = wave_max_f(m);
    if ((threadIdx.x & 63) == 0) sm[wid] = m;
    __syncthreads();
    m = fmaxf(fmaxf(sm[0], sm[1]), fmaxf(sm[2], sm[3]));
    float s = fmaxf(m, EPSQ) / 127.0f;   // same fp32 ops as reference

    char4* qr = (char4*)(q + (long)row * L);
    int isum = 0;
    for (int i = threadIdx.x; i < n4; i += 256) {
        float4 v = wr[i];
        int a = min(max((int)rintf(v.x / s), -128), 127);
        int bb = min(max((int)rintf(v.y / s), -128), 127);
        int c = min(max((int)rintf(v.z / s), -128), 127);
        int d = min(max((int)rintf(v.w / s), -128), 127);
        isum += a + bb + c + d;
        char4 cc; cc.x = (char)a; cc.y = (char)bb; cc.z = (char)c; cc.w = (char)d;
        qr[i] = cc;
    }
    isum = wave_sum_i(isum);
    if ((threadIdx.x & 63) == 0) si[wid] = isum;
    __syncthreads();
    if (threadIdx.x == 0) {
        s_out[row]  = s;
        rs_out[row] = si[0] + si[1] + si[2] + si[3];
    }
}

// ---------------- 1-block reducer: max(partials[0..n)) -> encoded slot ------
__global__ __launch_bounds__(256) void k_reduce_max(const float* __restrict__ partials,
                                                    int n, unsigned* __restrict__ slot) {
    __shared__ float sm[4];
    float m = -3.4e38f;
    for (int i = threadIdx.x; i < n; i += 256) m = fmaxf(m, partials[i]);
    m = wave_max_f(m);
    if ((threadIdx.x & 63) == 0) sm[threadIdx.x >> 6] = m;
    __syncthreads();
    if (threadIdx.x == 0)
        *slot = enc_f(fmaxf(fmaxf(sm[0], sm[1]), fmaxf(sm[2], sm[3])));
}

// ---------------- activation quant x -> int8 (offset -128) ----------------
__global__ __launch_bounds__(256) void k_quant_act(const float4* __restrict__ in,
                                                   char4* __restrict__ out, long n4,
                                                   const unsigned* __restrict__ slot) {
    float s = fmaxf(dec_f(*slot), EPSQ) / 255.0f;
    long i = (long)blockIdx.x * 256 + threadIdx.x;
    for (; i < n4; i += (long)gridDim.x * 256) {
        float4 v = in[i];
        int a = min(max((int)rintf(v.x / s), 0), 255) - 128;
        int b = min(max((int)rintf(v.y / s), 0), 255) - 128;
        int c = min(max((int)rintf(v.z / s), 0), 255) - 128;
        int d = min(max((int)rintf(v.w / s), 0), 255) - 128;
        char4 cc; cc.x = (char)a; cc.y = (char)b; cc.z = (char)c; cc.w = (char)d;
        out[i] = cc;
    }
}

// ---------------- async global -> LDS, 16B per lane ----------------
__device__ __forceinline__ void gl_lds16(const signed char* g, signed char* l) {
    __builtin_amdgcn_global_load_lds(
        (const __attribute__((address_space(1))) unsigned int*)g,
        (__attribute__((address_space(3))) unsigned int*)l, 16, 0, 0);
}

// ---------------- i8 GEMM, BK=128, 2-barrier (m97-proven shape) -------------
// LDS panel-major layout per slab (128 rows x 128 k-bytes = 16KB):
//   panel p (16 rows) at p*2048; byte (g*256 + r*16 + b) = row p*16+r, k g*16+b.
// Wave w stages its own contiguous 4KB (panels 2w,2w+1) with 8 gl_lds16;
// fragment reads are wave-contiguous 1024B ds_read_b128 (conflict-free).
// MODE 0: fp32 store (GEMM2); MODE 1: relu->global max only; MODE 2: relu->u8 quant store.
template<int MODE>
__global__ __launch_bounds__(256, 3) void k_gemm_i8(
    const signed char* __restrict__ A,   // [M][K]
    const signed char* __restrict__ B,   // [N][K]
    const float* __restrict__ s_w,       // [N]
    const int* __restrict__ rowsum,      // [N]
    const float* __restrict__ bias,      // [N]
    const unsigned* __restrict__ act_slot,
    float* __restrict__ Cf,              // MODE 0
    signed char* __restrict__ Cq,        // MODE 2
    unsigned* __restrict__ omax_slot,    // MODE 1: target; MODE 2: source
    int M, int N, long K) {
    __shared__ __align__(16) signed char Als[16384];
    __shared__ __align__(16) signed char Bls[16384];
    __shared__ float red[4];

    const int t    = threadIdx.x;
    const int lane = t & 63;
    const int w    = t >> 6;
    const int m0   = blockIdx.y * 128;
    const int n0   = blockIdx.x * 128;
    const int mr   = lane & 15;   // row-in-panel / C-D col-in-16
    const int qq   = lane >> 4;   // k-group / C-D row-quad

    // staging: lane fetches row (m0 + w*32 + mr [+16]), k-bytes (qq*16 [+64])
    const signed char* a0 = A + (long)(m0 + w * 32 + mr) * K + qq * 16;
    const signed char* b0 = B + (long)(n0 + w * 32 + mr) * K + qq * 16;
    signed char* ad = Als + w * 4096 + lane * 16;
    signed char* bd = Bls + w * 4096 + lane * 16;

    const int wrow = (w >> 1) * 64;
    const int wcol = (w & 1) * 64;
    const int a_base = (w >> 1) * 8192 + lane * 16;
    const int b_base = (w & 1) * 8192 + lane * 16;

    i32x4 acc[4][4];
    #pragma unroll
    for (int i = 0; i < 4; i++)
        #pragma unroll
        for (int j = 0; j < 4; j++) acc[i][j] = (i32x4){0, 0, 0, 0};

    for (long k0 = 0; k0 < K; k0 += 128) {
        __syncthreads();                    // previous iter's reads done
        gl_lds16(a0 + k0,               ad);
        gl_lds16(a0 + k0 + 64,          ad + 1024);
        gl_lds16(a0 + k0 + 16 * K,      ad + 2048);
        gl_lds16(a0 + k0 + 16 * K + 64, ad + 3072);
        gl_lds16(b0 + k0,               bd);
        gl_lds16(b0 + k0 + 64,          bd + 1024);
        gl_lds16(b0 + k0 + 16 * K,      bd + 2048);
        gl_lds16(b0 + k0 + 16 * K + 64, bd + 3072);
        __syncthreads();                    // vmcnt(0) drain: staging visible

        #pragma unroll
        for (int kk = 0; kk < 2; kk++) {
            i32x4 af[4], bf[4];
            #pragma unroll
            for (int i = 0; i < 4; i++)
                af[i] = *(const i32x4*)(Als + a_base + i * 2048 + kk * 1024);
            #pragma unroll
            for (int j = 0; j < 4; j++)
                bf[j] = *(const i32x4*)(Bls + b_base + j * 2048 + kk * 1024);
            #pragma unroll
            for (int i = 0; i < 4; i++)
                #pragma unroll
                for (int j = 0; j < 4; j++)
                    acc[i][j] = __builtin_amdgcn_mfma_i32_16x16x64_i8(
                        af[i], bf[j], acc[i][j], 0, 0, 0);
        }
    }

    // ---- epilogue ----
    const float s_act = fmaxf(dec_f(*act_slot), EPSQ) / 255.0f;

    if (MODE == 1) {
        // max(relu(h)); h = ssc*(v+bint) monotone in integer v per column
        float lmax = 0.0f;
        #pragma unroll
        for (int j = 0; j < 4; j++) {
            int im = -2147483647 - 1;
            #pragma unroll
            for (int i = 0; i < 4; i++)
                #pragma unroll
                for (int r = 0; r < 4; r++) im = max(im, acc[i][j][r]);
            int gn = n0 + wcol + j * 16 + mr;
            float ssc  = s_act * s_w[gn];
            float bint = rintf(bias[gn] / ssc);
            float h = ssc * ((float)(im + 128 * rowsum[gn]) + bint);
            lmax = fmaxf(lmax, h);
        }
        lmax = fmaxf(lmax, 0.0f);
        lmax = wave_max_f(lmax);
        if (lane == 0) red[w] = lmax;
        __syncthreads();
        if (t == 0)   // one atomic per block, staggered over the dispatch
            atomicMax(omax_slot,
                      enc_f(fmaxf(fmaxf(red[0], red[1]), fmaxf(red[2], red[3]))));
        return;
    }

    float s_oq = 1.0f;
    if (MODE == 2) s_oq = fmaxf(dec_f(*omax_slot), EPSQ) / 255.0f;

    #pragma unroll
    for (int j = 0; j < 4; j++) {
        int gn = n0 + wcol + j * 16 + mr;       // C/D col = lane&15
        float ssc  = s_act * s_w[gn];
        float bint = rintf(bias[gn] / ssc);
        int   icor = 128 * rowsum[gn];          // uint8 zero-point correction
        float fq   = (MODE == 2) ? (ssc / s_oq) : 0.0f;
        #pragma unroll
        for (int i = 0; i < 4; i++) {
            #pragma unroll
            for (int r = 0; r < 4; r++) {
                int gm = m0 + wrow + i * 16 + qq * 4 + r;  // C/D row
                float v = (float)(acc[i][j][r] + icor) + bint;
                if (MODE == 0) {
                    Cf[(long)gm * N + gn] = ssc * v;
                } else {
                    int qv = min(max((int)rintf(fq * v), 0), 255) - 128;
                    Cq[(long)gm * N + gn] = (signed char)qv;
                }
            }
        }
    }
}

extern "C" void kernel_launch(void* const* d_in, const int* in_sizes, int n_in,
                              void* d_out, int out_size, void* d_ws, size_t ws_size,
                              hipStream_t stream) {
    const float* x  = (const float*)d_in[0];  // [4,2048,1024]
    const float* w1 = (const float*)d_in[1];  // [4096,1024]
    const float* b1 = (const float*)d_in[2];  // [4096]
    const float* w2 = (const float*)d_in[3];  // [1024,4096]
    const float* b2 = (const float*)d_in[4];  // [1024]
    float* out = (float*)d_out;               // [4,2048,1024] fp32

    const int M = 8192, D = 1024, F = 4096;

    char* ws = (char*)d_ws;
    size_t off = 0;
    unsigned* slots = (unsigned*)ws;               off += 256;  // [0]=max x, [1]=max h
    float* partials = (float*)(ws + off);          off += 2048 * 4;
    signed char* xi  = (signed char*)(ws + off);   off += (size_t)M * D;  // 8 MB
    signed char* w1q = (signed char*)(ws + off);   off += (size_t)F * D;  // 4 MB
    signed char* w2q = (signed char*)(ws + off);   off += (size_t)D * F;  // 4 MB
    float* sw1 = (float*)(ws + off);               off += (size_t)F * 4;
    float* sw2 = (float*)(ws + off);               off += (size_t)D * 4;
    int* rs1   = (int*)(ws + off);                 off += (size_t)F * 4;
    int* rs2   = (int*)(ws + off);                 off += (size_t)D * 4;
    signed char* hq = (signed char*)(ws + off);    off += (size_t)M * F;  // 32 MB

    hipMemsetAsync(slots, 0, 8, stream);  // slots[1]=0 < any encoded real value

    k_prep<<<dim3(2048 + F + D), dim3(256), 0, stream>>>(
        (const float4*)x, (long)M * D / 4, partials,
        w1, w1q, sw1, rs1, w2, w2q, sw2, rs2);
    k_reduce_max<<<dim3(1), dim3(256), 0, stream>>>(partials, 2048, slots + 0);
    k_quant_act<<<dim3(2048), dim3(256), 0, stream>>>((const float4*)x, (char4*)xi,
                                                      (long)M * D / 4, slots + 0);
    // GEMM1 pass 1: max(relu(h)) only
    k_gemm_i8<1><<<dim3(F / 128, M / 128), dim3(256), 0, stream>>>(
        xi, w1q, sw1, rs1, b1, slots + 0, nullptr, nullptr, slots + 1, M, F, (long)D);
    // GEMM1 pass 2: write quantized h (int8, offset -128)
    k_gemm_i8<2><<<dim3(F / 128, M / 128), dim3(256), 0, stream>>>(
        xi, w1q, sw1, rs1, b1, slots + 0, nullptr, hq, slots + 1, M, F, (long)D);
    // GEMM2: fp32 output
    k_gemm_i8<0><<<dim3(D / 128, M / 128), dim3(256), 0, stream>>>(
        hq, w2q, sw2, rs2, b2, slots + 1, out, nullptr, nullptr, M, D, (long)F);

    (void)in_sizes; (void)n_in; (void)out_size; (void)ws_size;
}